// Round 2
// baseline (1394.063 us; speedup 1.0000x reference)
//
#include <hip/hip_runtime.h>
#include <math.h>

#define S_LEN  2048
#define B_SZ   256
#define T_TAGS 48

// ---------------------------------------------------------------------------
// Forward algorithm (normalizer), linear space, register-resident state.
// One wave per batch element. Lane j owns v[j]. Broadcast of the 48 old
// v values via v_readlane (-> SGPRs), matvec as 48 v_fma with SGPR operand.
// Renormalization: divide by 2^k where k = floor(log2(old v[0])), extracted
// with integer ops on the SALU pipe; accumulate integer K; exact scaling.
// true_score[j] = log(v[j]) + K*ln2.
// ---------------------------------------------------------------------------
__global__ __launch_bounds__(64, 1) void crf_forward_kernel(
    const float* __restrict__ em, const int* __restrict__ mask,
    const float* __restrict__ startT, const float* __restrict__ endT,
    const float* __restrict__ trans, float* __restrict__ out)
{
    const int b   = blockIdx.x;
    const int tid = threadIdx.x;                 // 0..63
    const int j   = (tid < T_TAGS) ? tid : 0;    // lanes 48..63 shadow lane 0

    // expT column j in registers (constant over s)
    float expT[T_TAGS];
#pragma unroll
    for (int i = 0; i < T_TAGS; ++i)
        expT[i] = __expf(trans[i * T_TAGS + j]);

    const float endv = __expf(endT[j]);

    // init: v[j] = exp(start[j] + em[0,b,j])
    float v = __expf(startT[j] + em[(size_t)b * T_TAGS + j]);

    int K = 0;

    // emission/mask prefetch ring, depth 8
    float em_pf[8];
    int   mk_pf[8];
#pragma unroll
    for (int k = 0; k < 8; ++k) {
        int ss = 1 + k; if (ss > S_LEN - 1) ss = S_LEN - 1;
        em_pf[k] = em[((size_t)ss * B_SZ + b) * T_TAGS + j];
        mk_pf[k] = mask[ss * B_SZ + b];
    }

#pragma unroll 8
    for (int s = 1; s < S_LEN; ++s) {
        const int   slot   = (s - 1) & 7;        // static under unroll-8
        const float em_cur = em_pf[slot];
        const int   mk_cur = mk_pf[slot];
        int sp = s + 8; if (sp > S_LEN - 1) sp = S_LEN - 1;
        em_pf[slot] = em[((size_t)sp * B_SZ + b) * T_TAGS + j];
        mk_pf[slot] = mask[sp * B_SZ + b];

        // broadcast all 48 old-v values into uniform (SGPR) scalars
        float sc[T_TAGS];
#pragma unroll
        for (int i = 0; i < T_TAGS; ++i)
            sc[i] = __uint_as_float(
                __builtin_amdgcn_readlane(__float_as_uint(v), i));

        float a0 = 0.f, a1 = 0.f, a2 = 0.f, a3 = 0.f;
#pragma unroll
        for (int i = 0; i < T_TAGS; i += 4) {
            a0 = fmaf(sc[i + 0], expT[i + 0], a0);
            a1 = fmaf(sc[i + 1], expT[i + 1], a1);
            a2 = fmaf(sc[i + 2], expT[i + 2], a2);
            a3 = fmaf(sc[i + 3], expT[i + 3], a3);
        }
        const float ssum = (a0 + a1) + (a2 + a3);

        // power-of-two renorm from old v[0] (uniform -> SALU integer ops)
        const unsigned bits = __float_as_uint(sc[0]);
        const int      e    = (int)((bits >> 23) & 0xFFu);
        const int      k    = e - 127;
        const float    scale = __uint_as_float((unsigned)(254 - e) << 23);

        const float vn = ssum * __expf(em_cur) * scale;
        v = (mk_cur != 0) ? vn : v;
        K += (mk_cur != 0) ? k : 0;
    }

    // denominator_b = K*ln2 + log( sum_j v[j]*exp(end[j]) )
    float contrib = (tid < T_TAGS) ? v * endv : 0.0f;
#pragma unroll
    for (int off = 32; off > 0; off >>= 1)
        contrib += __shfl_down(contrib, off);
    if (tid == 0) {
        const double den = (double)K * 0.6931471805599453
                         + (double)__logf(contrib);
        atomicAdd(out, (float)(-den));
    }
}

// ---------------------------------------------------------------------------
// Numerator: emission scores of chosen tags + transition scores + start terms
// ---------------------------------------------------------------------------
__global__ void crf_num_kernel(
    const float* __restrict__ em, const int* __restrict__ tags,
    const int* __restrict__ mask, const float* __restrict__ startT,
    const float* __restrict__ trans, float* __restrict__ out)
{
    const int N = S_LEN * B_SZ;
    float acc = 0.f;
    for (int idx = blockIdx.x * blockDim.x + threadIdx.x; idx < N;
         idx += gridDim.x * blockDim.x) {
        const int t = tags[idx];
        const float e = em[(size_t)idx * T_TAGS + t];
        if (idx < B_SZ) {                         // s == 0
            acc += e + startT[t];
        } else if (mask[idx] != 0) {
            acc += e + trans[tags[idx - B_SZ] * T_TAGS + t];
        }
    }
#pragma unroll
    for (int off = 32; off > 0; off >>= 1)
        acc += __shfl_down(acc, off);
    if ((threadIdx.x & 63) == 0) atomicAdd(out, acc);
}

// ---------------------------------------------------------------------------
// End-transition terms: seq_ends = mask.sum(0) - 1; end[tags[seq_end, b]]
// ---------------------------------------------------------------------------
__global__ void crf_end_kernel(
    const int* __restrict__ tags, const int* __restrict__ mask,
    const float* __restrict__ endT, float* __restrict__ out)
{
    const int b = blockIdx.x * blockDim.x + threadIdx.x;
    float acc = 0.f;
    if (b < B_SZ) {
        int cnt = 0;
        for (int s = 0; s < S_LEN; ++s) cnt += (mask[s * B_SZ + b] != 0);
        const int last = tags[(size_t)(cnt - 1) * B_SZ + b];
        acc = endT[last];
    }
#pragma unroll
    for (int off = 32; off > 0; off >>= 1)
        acc += __shfl_down(acc, off);
    if ((threadIdx.x & 63) == 0) atomicAdd(out, acc);
}

extern "C" void kernel_launch(void* const* d_in, const int* in_sizes, int n_in,
                              void* d_out, int out_size, void* d_ws, size_t ws_size,
                              hipStream_t stream)
{
    const float* em     = (const float*)d_in[0];
    const int*   tags   = (const int*)  d_in[1];
    const int*   mask   = (const int*)  d_in[2];
    const float* startT = (const float*)d_in[3];
    const float* endT   = (const float*)d_in[4];
    const float* trans  = (const float*)d_in[5];
    float* out = (float*)d_out;

    hipMemsetAsync(out, 0, sizeof(float), stream);
    crf_forward_kernel<<<B_SZ, 64, 0, stream>>>(em, mask, startT, endT, trans, out);
    crf_num_kernel<<<512, 256, 0, stream>>>(em, tags, mask, startT, trans, out);
    crf_end_kernel<<<1, 256, 0, stream>>>(tags, mask, endT, out);
}

// Round 3
// 1057.129 us; speedup vs baseline: 1.3187x; 1.3187x over previous
//
#include <hip/hip_runtime.h>
#include <math.h>

#define S_LEN  2048
#define B_SZ   256
#define T_TAGS 48

// ---------------------------------------------------------------------------
// Forward algorithm (normalizer), linear space, register-resident state.
// One wave per batch element. Lane j owns v[j]. Broadcast of the 48 old
// v values via v_readlane (constant lane index -> SGPRs), matvec as 48
// v_fma with SGPR operand. Renormalization by exact power-of-two scaling
// extracted from v[0]'s exponent field; integer K accumulates the log2.
// NO memory operations inside the recurrence: mask is bit-packed into one
// VGPR per lane at startup (lane l holds s = l+64k), emissions flow through
// an 8-deep per-lane vector prefetch ring (vmcnt-pipelined).
// ---------------------------------------------------------------------------
__global__ __launch_bounds__(64, 1) void crf_forward_kernel(
    const float* __restrict__ em, const int* __restrict__ mask,
    const float* __restrict__ startT, const float* __restrict__ endT,
    const float* __restrict__ trans, float* __restrict__ out)
{
    const int b   = blockIdx.x;
    const int tid = threadIdx.x;                 // 0..63
    const int j   = (tid < T_TAGS) ? tid : 0;    // lanes 48..63 shadow lane 0

    // ---- startup: mask bitpack (lane l -> bits for s = l + 64k) ----
    unsigned mbits = 0;
#pragma unroll
    for (int k = 0; k < 32; ++k) {
        const int s = tid + 64 * k;              // covers 0..2047 exactly
        mbits |= (mask[s * B_SZ + b] != 0 ? 1u : 0u) << k;
    }

    // ---- startup: expT column j in registers (constant over s) ----
    float expT[T_TAGS];
#pragma unroll
    for (int i = 0; i < T_TAGS; ++i)
        expT[i] = __expf(trans[i * T_TAGS + j]);

    const float endv = __expf(endT[j]);

    // init: v[j] = exp(start[j] + em[0,b,j])
    float v = __expf(startT[j] + em[(size_t)b * T_TAGS + j]);

    int K = 0;

    // emission prefetch ring, depth 8 (per-lane vector loads, vmcnt-counted)
    float em_pf[8];
#pragma unroll
    for (int k = 0; k < 8; ++k) {
        int ss = 1 + k; if (ss > S_LEN - 1) ss = S_LEN - 1;
        em_pf[k] = em[((size_t)ss * B_SZ + b) * T_TAGS + j];
    }

#pragma unroll 8
    for (int s = 1; s < S_LEN; ++s) {
        const int   slot   = (s - 1) & 7;        // static under unroll-8
        const float em_cur = em_pf[slot];
        int sp = s + 8; if (sp > S_LEN - 1) sp = S_LEN - 1;
        em_pf[slot] = em[((size_t)sp * B_SZ + b) * T_TAGS + j];

        // mask bit for step s: lane (s&63), bit (s>>6) -- no memory access
        const unsigned mrow = __builtin_amdgcn_readlane(mbits, s & 63);
        const bool     mk   = (mrow >> (s >> 6)) & 1u;

        // broadcast all 48 old-v values into uniform (SGPR) scalars
        float sc[T_TAGS];
#pragma unroll
        for (int i = 0; i < T_TAGS; ++i)
            sc[i] = __uint_as_float(
                __builtin_amdgcn_readlane(__float_as_uint(v), i));

        float a0 = 0.f, a1 = 0.f, a2 = 0.f, a3 = 0.f;
#pragma unroll
        for (int i = 0; i < T_TAGS; i += 4) {
            a0 = fmaf(sc[i + 0], expT[i + 0], a0);
            a1 = fmaf(sc[i + 1], expT[i + 1], a1);
            a2 = fmaf(sc[i + 2], expT[i + 2], a2);
            a3 = fmaf(sc[i + 3], expT[i + 3], a3);
        }
        const float ssum = (a0 + a1) + (a2 + a3);

        // power-of-two renorm from old v[0] (uniform -> SALU integer ops)
        const unsigned bits = __float_as_uint(sc[0]);
        const int      e    = (int)((bits >> 23) & 0xFFu);
        const int      k    = e - 127;
        const float    scale = __uint_as_float((unsigned)(254 - e) << 23);

        const float vn = ssum * __expf(em_cur) * scale;
        v = mk ? vn : v;
        K += mk ? k : 0;
    }

    // denominator_b = K*ln2 + log( sum_j v[j]*exp(end[j]) )
    float contrib = (tid < T_TAGS) ? v * endv : 0.0f;
#pragma unroll
    for (int off = 32; off > 0; off >>= 1)
        contrib += __shfl_down(contrib, off);
    if (tid == 0) {
        const double den = (double)K * 0.6931471805599453
                         + (double)__logf(contrib);
        atomicAdd(out, (float)(-den));
    }
}

// ---------------------------------------------------------------------------
// Numerator: emission scores of chosen tags + transition scores + start terms
// ---------------------------------------------------------------------------
__global__ void crf_num_kernel(
    const float* __restrict__ em, const int* __restrict__ tags,
    const int* __restrict__ mask, const float* __restrict__ startT,
    const float* __restrict__ trans, float* __restrict__ out)
{
    const int N = S_LEN * B_SZ;
    float acc = 0.f;
    for (int idx = blockIdx.x * blockDim.x + threadIdx.x; idx < N;
         idx += gridDim.x * blockDim.x) {
        const int t = tags[idx];
        const float e = em[(size_t)idx * T_TAGS + t];
        if (idx < B_SZ) {                         // s == 0
            acc += e + startT[t];
        } else if (mask[idx] != 0) {
            acc += e + trans[tags[idx - B_SZ] * T_TAGS + t];
        }
    }
#pragma unroll
    for (int off = 32; off > 0; off >>= 1)
        acc += __shfl_down(acc, off);
    if ((threadIdx.x & 63) == 0) atomicAdd(out, acc);
}

// ---------------------------------------------------------------------------
// End-transition terms: seq_ends = mask.sum(0) - 1; end[tags[seq_end, b]]
// ---------------------------------------------------------------------------
__global__ void crf_end_kernel(
    const int* __restrict__ tags, const int* __restrict__ mask,
    const float* __restrict__ endT, float* __restrict__ out)
{
    const int b = blockIdx.x * blockDim.x + threadIdx.x;
    float acc = 0.f;
    if (b < B_SZ) {
        int cnt = 0;
        for (int s = 0; s < S_LEN; ++s) cnt += (mask[s * B_SZ + b] != 0);
        const int last = tags[(size_t)(cnt - 1) * B_SZ + b];
        acc = endT[last];
    }
#pragma unroll
    for (int off = 32; off > 0; off >>= 1)
        acc += __shfl_down(acc, off);
    if ((threadIdx.x & 63) == 0) atomicAdd(out, acc);
}

extern "C" void kernel_launch(void* const* d_in, const int* in_sizes, int n_in,
                              void* d_out, int out_size, void* d_ws, size_t ws_size,
                              hipStream_t stream)
{
    const float* em     = (const float*)d_in[0];
    const int*   tags   = (const int*)  d_in[1];
    const int*   mask   = (const int*)  d_in[2];
    const float* startT = (const float*)d_in[3];
    const float* endT   = (const float*)d_in[4];
    const float* trans  = (const float*)d_in[5];
    float* out = (float*)d_out;

    hipMemsetAsync(out, 0, sizeof(float), stream);
    crf_forward_kernel<<<B_SZ, 64, 0, stream>>>(em, mask, startT, endT, trans, out);
    crf_num_kernel<<<512, 256, 0, stream>>>(em, tags, mask, startT, trans, out);
    crf_end_kernel<<<1, 256, 0, stream>>>(tags, mask, endT, out);
}

// Round 4
// 292.684 us; speedup vs baseline: 4.7630x; 3.6118x over previous
//
#include <hip/hip_runtime.h>
#include <hip/hip_bf16.h>
#include <math.h>

#define S_LEN  2048
#define B_SZ   256
#define T_TAGS 48
#define C_CH   8                  // chunks per sequence
#define L_CH   256                // steps per chunk
#define NCHUNK (B_SZ * C_CH)      // 2048
#define PROW   72                 // padded LDS row in bf16 elems (144B stride)
#define WS_MAT_U32 1152           // 48 rows * 24 u32 per chunk matrix
#define WS_K_OFF  ((size_t)NCHUNK * 4608)

using short8 = __attribute__((ext_vector_type(8))) short;
using f32x4  = __attribute__((ext_vector_type(4))) float;

__device__ __forceinline__ unsigned short f2bf(float x) {
    __hip_bfloat16 h = __float2bfloat16(x);
    return *reinterpret_cast<unsigned short*>(&h);
}
__device__ __forceinline__ unsigned pk2bf(float lo, float hi) {
    __hip_bfloat162 h2 = __float22bfloat162_rn(make_float2(lo, hi));
    return *reinterpret_cast<unsigned*>(&h2);
}

// ---------------------------------------------------------------------------
// Phase 1: per-chunk transfer matrix P_c = Prod_{s in chunk} M_s, where
// M_s[i][j] = expT[i][j]*exp(em[s,j]) (mask=1) or I (mask=0), with exact
// power-of-2 renorm tracked in integer K. One wave per chunk; P^T kept in
// LDS as Pl[i][j] (bf16, row-padded); per step: 6 ds_read_b128 (B frags),
// 18 MFMA 16x16x32 bf16 (A = const expT^T frags), probe-renorm, e-scale,
// 9 ds_write_b64. Same-wave DS ordering => no barriers.
// ---------------------------------------------------------------------------
__global__ __launch_bounds__(64, 4) void crf_chunk_kernel(
    const float* __restrict__ em, const int* __restrict__ mask,
    const float* __restrict__ trans, unsigned* __restrict__ wsP,
    int* __restrict__ wsK)
{
    const int bid = blockIdx.x;
    const int b = bid >> 3, c = bid & 7;
    const int tid = threadIdx.x;
    const int cc = tid & 15, g = tid >> 4;

    __shared__ unsigned short Pl[T_TAGS][PROW];

    // identity init (also zeroes the j>=48 pad read by kt=1 fragments)
    for (int idx = tid; idx < T_TAGS * PROW; idx += 64) {
        const int r = idx / PROW, cl = idx - r * PROW;
        Pl[r][cl] = (r == cl) ? (unsigned short)0x3F80 : (unsigned short)0;
    }

    // constant A fragments: A(jt,kt), A[j][k] = expT[k][j] = exp(trans[k*48+j])
    // A-layout: row j = jt*16 + (lane&15); k = kt*32 + (lane>>4)*8 + e
    short8 A[3][2];
#pragma unroll
    for (int jt = 0; jt < 3; ++jt) {
        const int j = jt * 16 + cc;
#pragma unroll
        for (int kt = 0; kt < 2; ++kt) {
            short8 a;
#pragma unroll
            for (int e = 0; e < 8; ++e) {
                const int k = kt * 32 + g * 8 + e;
                const float v = (k < T_TAGS) ? __expf(trans[k * T_TAGS + j]) : 0.f;
                a[e] = (short)f2bf(v);
            }
            A[jt][kt] = a;
        }
    }

    // mask bits for this chunk (bit t of ball[t>>6] = mask at step c*L+t)
    unsigned long long ball[4];
#pragma unroll
    for (int q = 0; q < 4; ++q) {
        const int s = c * L_CH + q * 64 + tid;
        ball[q] = __ballot(mask[s * B_SZ + b] != 0);
    }

    int K = 0;
    const int tstart = (c == 0) ? 1 : 0;   // global step s=0 is the init, not a transition
    const size_t embase = (size_t)b * T_TAGS + 4 * g;

    // em prefetch (3 float4 pieces = the 12 e-values this lane-group needs)
    f32x4 pf0, pf1, pf2;
    {
        const size_t o = (size_t)(c * L_CH + tstart) * (B_SZ * T_TAGS) + embase;
        pf0 = *reinterpret_cast<const f32x4*>(&em[o]);
        pf1 = *reinterpret_cast<const f32x4*>(&em[o + 16]);
        pf2 = *reinterpret_cast<const f32x4*>(&em[o + 32]);
    }

#pragma unroll 2
    for (int t = tstart; t < L_CH; ++t) {
        const int s = c * L_CH + t;
        const f32x4 cur0 = pf0, cur1 = pf1, cur2 = pf2;
        {
            const int sp = (s + 1 < S_LEN) ? s + 1 : S_LEN - 1;
            const size_t o = (size_t)sp * (B_SZ * T_TAGS) + embase;
            pf0 = *reinterpret_cast<const f32x4*>(&em[o]);
            pf1 = *reinterpret_cast<const f32x4*>(&em[o + 16]);
            pf2 = *reinterpret_cast<const f32x4*>(&em[o + 32]);
        }
        if ((ball[t >> 6] >> (t & 63)) & 1ull) {
            // B fragments: B[k][n] = P[n][k]; read Pl[nt*16+cc][kt*32+g*8 ..]
            short8 Bf[2][3];
#pragma unroll
            for (int nt = 0; nt < 3; ++nt)
#pragma unroll
                for (int kt = 0; kt < 2; ++kt)
                    Bf[kt][nt] = *reinterpret_cast<const short8*>(
                        &Pl[nt * 16 + cc][kt * 32 + g * 8]);

            f32x4 acc[3][3];
#pragma unroll
            for (int jt = 0; jt < 3; ++jt)
#pragma unroll
                for (int nt = 0; nt < 3; ++nt) {
                    f32x4 z = {0.f, 0.f, 0.f, 0.f};
                    z = __builtin_amdgcn_mfma_f32_16x16x32_bf16(A[jt][0], Bf[0][nt], z, 0, 0, 0);
                    z = __builtin_amdgcn_mfma_f32_16x16x32_bf16(A[jt][1], Bf[1][nt], z, 0, 0, 0);
                    acc[jt][nt] = z;
                }

            // uniform power-of-2 renorm from one accumulator entry
            const unsigned pbits = (unsigned)__builtin_amdgcn_readfirstlane(
                (int)__float_as_uint(acc[0][0][0]));
            const int ee = (int)((pbits >> 23) & 255u);
            K += ee - 127;
            const float scalef = __uint_as_float((unsigned)(254 - ee) << 23);

            // scale row j by exp(em[s,j])*2^-k, pack bf16, write back
#pragma unroll
            for (int jt = 0; jt < 3; ++jt) {
                const f32x4 emv = (jt == 0) ? cur0 : (jt == 1) ? cur1 : cur2;
                const float e0 = __expf(emv[0]) * scalef;
                const float e1 = __expf(emv[1]) * scalef;
                const float e2 = __expf(emv[2]) * scalef;
                const float e3 = __expf(emv[3]) * scalef;
#pragma unroll
                for (int nt = 0; nt < 3; ++nt) {
                    const f32x4 a = acc[jt][nt];
                    const unsigned u0 = pk2bf(a[0] * e0, a[1] * e1);
                    const unsigned u1 = pk2bf(a[2] * e2, a[3] * e3);
                    *reinterpret_cast<uint2*>(&Pl[nt * 16 + cc][jt * 16 + 4 * g]) =
                        make_uint2(u0, u1);
                }
            }
        }
    }

    // write out column j of P (= row j of stored layout) as 24 packed u32
    if (tid < T_TAGS) {
        const unsigned base = (unsigned)bid * WS_MAT_U32 + tid * 24;
#pragma unroll
        for (int q = 0; q < 6; ++q) {
            uint4 W;
            W.x = (unsigned)Pl[8 * q + 0][tid] | ((unsigned)Pl[8 * q + 1][tid] << 16);
            W.y = (unsigned)Pl[8 * q + 2][tid] | ((unsigned)Pl[8 * q + 3][tid] << 16);
            W.z = (unsigned)Pl[8 * q + 4][tid] | ((unsigned)Pl[8 * q + 5][tid] << 16);
            W.w = (unsigned)Pl[8 * q + 6][tid] | ((unsigned)Pl[8 * q + 7][tid] << 16);
            *reinterpret_cast<uint4*>(&wsP[base + 4 * q]) = W;
        }
    }
    if (tid == 0) wsK[bid] = K;
}

// ---------------------------------------------------------------------------
// Phase 2: per-sequence combine over 8 chunk matrices, then endT + log.
// ---------------------------------------------------------------------------
__global__ __launch_bounds__(64, 1) void crf_combine_kernel(
    const float* __restrict__ em, const float* __restrict__ startT,
    const float* __restrict__ endT, const unsigned* __restrict__ wsP,
    const int* __restrict__ wsK, float* __restrict__ out)
{
    const int b = blockIdx.x, tid = threadIdx.x;
    const int j = (tid < T_TAGS) ? tid : 0;
    float v = (tid < T_TAGS) ? __expf(startT[j] + em[(size_t)b * T_TAGS + j]) : 0.f;
    int K2 = 0;
    for (int c = 0; c < C_CH; ++c) {
        const unsigned base = (unsigned)(b * C_CH + c) * WS_MAT_U32 + j * 24;
        uint4 W[6];
#pragma unroll
        for (int q = 0; q < 6; ++q)
            W[q] = *reinterpret_cast<const uint4*>(&wsP[base + 4 * q]);
        float a0 = 0.f, a1 = 0.f;
#pragma unroll
        for (int q = 0; q < 6; ++q) {
            const unsigned wv[4] = {W[q].x, W[q].y, W[q].z, W[q].w};
#pragma unroll
            for (int r = 0; r < 4; ++r) {
                const int i = q * 8 + r * 2;
                const float p0 = __uint_as_float(wv[r] << 16);
                const float p1 = __uint_as_float(wv[r] & 0xFFFF0000u);
                a0 = fmaf(__uint_as_float(__builtin_amdgcn_readlane(__float_as_uint(v), i)), p0, a0);
                a1 = fmaf(__uint_as_float(__builtin_amdgcn_readlane(__float_as_uint(v), i + 1)), p1, a1);
            }
        }
        const float vn = a0 + a1;
        const unsigned pb = (unsigned)__builtin_amdgcn_readfirstlane((int)__float_as_uint(vn));
        const int ee = (int)((pb >> 23) & 255u);
        const float sc = __uint_as_float((unsigned)(254 - ee) << 23);
        v = vn * sc;
        K2 += (ee - 127) + wsK[b * C_CH + c];
    }
    float contrib = (tid < T_TAGS) ? v * __expf(endT[j]) : 0.f;
#pragma unroll
    for (int off = 32; off > 0; off >>= 1) contrib += __shfl_down(contrib, off);
    if (tid == 0) {
        const double den = (double)K2 * 0.6931471805599453 + (double)__logf(contrib);
        atomicAdd(out, (float)(-den));
    }
}

// ---------------------------------------------------------------------------
// Numerator: emission scores of chosen tags + transition scores + start terms
// ---------------------------------------------------------------------------
__global__ void crf_num_kernel(
    const float* __restrict__ em, const int* __restrict__ tags,
    const int* __restrict__ mask, const float* __restrict__ startT,
    const float* __restrict__ trans, float* __restrict__ out)
{
    const int N = S_LEN * B_SZ;
    float acc = 0.f;
    for (int idx = blockIdx.x * blockDim.x + threadIdx.x; idx < N;
         idx += gridDim.x * blockDim.x) {
        const int t = tags[idx];
        const float e = em[(size_t)idx * T_TAGS + t];
        if (idx < B_SZ) {                         // s == 0
            acc += e + startT[t];
        } else if (mask[idx] != 0) {
            acc += e + trans[tags[idx - B_SZ] * T_TAGS + t];
        }
    }
#pragma unroll
    for (int off = 32; off > 0; off >>= 1)
        acc += __shfl_down(acc, off);
    if ((threadIdx.x & 63) == 0) atomicAdd(out, acc);
}

// ---------------------------------------------------------------------------
// End-transition terms, one block per sequence
// ---------------------------------------------------------------------------
__global__ __launch_bounds__(64, 1) void crf_end_kernel(
    const int* __restrict__ tags, const int* __restrict__ mask,
    const float* __restrict__ endT, float* __restrict__ out)
{
    const int b = blockIdx.x, tid = threadIdx.x;
    int cnt = 0;
    for (int s = tid; s < S_LEN; s += 64) cnt += (mask[s * B_SZ + b] != 0);
#pragma unroll
    for (int off = 32; off > 0; off >>= 1) cnt += __shfl_down(cnt, off);
    if (tid == 0) {
        const int last = tags[(size_t)(cnt - 1) * B_SZ + b];
        atomicAdd(out, endT[last]);
    }
}

extern "C" void kernel_launch(void* const* d_in, const int* in_sizes, int n_in,
                              void* d_out, int out_size, void* d_ws, size_t ws_size,
                              hipStream_t stream)
{
    const float* em     = (const float*)d_in[0];
    const int*   tags   = (const int*)  d_in[1];
    const int*   mask   = (const int*)  d_in[2];
    const float* startT = (const float*)d_in[3];
    const float* endT   = (const float*)d_in[4];
    const float* trans  = (const float*)d_in[5];
    float* out = (float*)d_out;

    unsigned* wsP = (unsigned*)d_ws;
    int*      wsK = (int*)((char*)d_ws + WS_K_OFF);

    hipMemsetAsync(out, 0, sizeof(float), stream);
    crf_chunk_kernel<<<NCHUNK, 64, 0, stream>>>(em, mask, trans, wsP, wsK);
    crf_combine_kernel<<<B_SZ, 64, 0, stream>>>(em, startT, endT, wsP, wsK, out);
    crf_num_kernel<<<512, 256, 0, stream>>>(em, tags, mask, startT, trans, out);
    crf_end_kernel<<<B_SZ, 64, 0, stream>>>(tags, mask, endT, out);
}

// Round 5
// 280.500 us; speedup vs baseline: 4.9699x; 1.0434x over previous
//
#include <hip/hip_runtime.h>
#include <hip/hip_bf16.h>
#include <math.h>

#define S_LEN  2048
#define B_SZ   256
#define T_TAGS 48
#define PROW   72
#define MAT_U32 1152          // 48 rows * 24 u32 (bf16-packed 48x48)

#define WS_CNT_OFF 0          // 256 ints
#define WS_K_OFF   1024       // up to 4096 ints
#define WS_P_OFF   32768      // chunk matrices

using short8 = __attribute__((ext_vector_type(8))) short;
using f32x4  = __attribute__((ext_vector_type(4))) float;

__device__ __forceinline__ unsigned pk2bf(float lo, float hi) {
    __hip_bfloat162 h2 = __float22bfloat162_rn(make_float2(lo, hi));
    return *reinterpret_cast<unsigned*>(&h2);
}

// ---------------------------------------------------------------------------
// Phase 1: per-chunk transfer matrix with pre-scaled A operand and
// fold-forward power-of-2 renormalization. One wave per chunk.
// Per step: 6 ds_read_b128 (B frags), 3 exp + A-rebuild (72 VALU),
// 18 MFMA 16x16x32 bf16, probe (SALU), 18 cvt_pk + 9 ds_write_b64.
// Same-wave DS ordering => no barriers.
// ---------------------------------------------------------------------------
template<int CCH>
__global__ __launch_bounds__(64, 4) void crf_chunk_kernel(
    const float* __restrict__ em, const int* __restrict__ mask,
    const float* __restrict__ trans, unsigned* __restrict__ wsP,
    int* __restrict__ wsK, int* __restrict__ wsCnt)
{
    constexpr int LCH = S_LEN / CCH;
    constexpr int NQ  = LCH / 64;
    const int bid = blockIdx.x;
    const int b = bid / CCH, c = bid % CCH;
    const int tid = threadIdx.x;
    const int cc = tid & 15, g = tid >> 4;
    const bool c0 = (c == 0);

    __shared__ __align__(16) unsigned short Pl[T_TAGS][PROW];

    // identity init (pad cols >=48 stay zero; read by kt=1 g>=2 frags)
    for (int idx = tid; idx < T_TAGS * PROW; idx += 64) {
        const int r = idx / PROW, cl = idx - r * PROW;
        Pl[r][cl] = (r == cl) ? (unsigned short)0x3F80 : (unsigned short)0;
    }

    // expT in fp32: expTf[jt][kt][e] = exp(trans[k][j]), j=jt*16+cc, k=kt*32+g*8+e
    float expTf[3][2][8];
#pragma unroll
    for (int jt = 0; jt < 3; ++jt) {
        const int j = jt * 16 + cc;
#pragma unroll
        for (int kt = 0; kt < 2; ++kt)
#pragma unroll
            for (int e = 0; e < 8; ++e) {
                const int k = kt * 32 + g * 8 + e;
                expTf[jt][kt][e] = (k < T_TAGS) ? __expf(trans[k * T_TAGS + j]) : 0.f;
            }
    }

    // mask ballots for this chunk
    unsigned long long ball[NQ];
    int cnt = 0;
#pragma unroll
    for (int q = 0; q < NQ; ++q) {
        const int s = c * LCH + q * 64 + tid;
        ball[q] = __ballot(mask[s * B_SZ + b] != 0);
        cnt += (int)__popcll(ball[q]);
    }
    if (tid == 0) atomicAdd(&wsCnt[b], cnt);

    int K = 0, pend = 0;
    float pscale = 1.0f;

#define EMLOAD(T, D0, D1, D2) do {                                          \
        int ss_ = c * LCH + (T); if (ss_ > S_LEN - 1) ss_ = S_LEN - 1;      \
        const float* p_ = em + ((size_t)ss_ * B_SZ + b) * T_TAGS + cc;      \
        D0 = p_[0]; D1 = p_[16]; D2 = p_[32];                               \
    } while (0)

#define MKA(JT, KT, EF) ({                                                   \
        uint4 uu_ = make_uint4(                                              \
            pk2bf(expTf[JT][KT][0] * (EF), expTf[JT][KT][1] * (EF)),         \
            pk2bf(expTf[JT][KT][2] * (EF), expTf[JT][KT][3] * (EF)),         \
            pk2bf(expTf[JT][KT][4] * (EF), expTf[JT][KT][5] * (EF)),         \
            pk2bf(expTf[JT][KT][6] * (EF), expTf[JT][KT][7] * (EF)));        \
        *reinterpret_cast<short8*>(&uu_); })

#define DOFRAG(Z, A0, A1, NT, JT) do {                                       \
        f32x4 z_ = {0.f, 0.f, 0.f, 0.f};                                     \
        z_ = __builtin_amdgcn_mfma_f32_16x16x32_bf16(A0, Bf0##NT, z_, 0, 0, 0);\
        z_ = __builtin_amdgcn_mfma_f32_16x16x32_bf16(A1, Bf1##NT, z_, 0, 0, 0);\
        Z = z_;                                                              \
    } while (0)

#define WRFRAG(Z, NT, JT)                                                    \
        *reinterpret_cast<uint2*>(&Pl[(NT) * 16 + cc][(JT) * 16 + 4 * g]) =  \
            make_uint2(pk2bf(Z[0], Z[1]), pk2bf(Z[2], Z[3]))

#define STEP_BODY(SKIP0, BIT, E0, E1, E2) do {                               \
    const bool proc_ = (((bq >> (BIT)) & 1ull) != 0) && !(SKIP0);            \
    if (proc_) {                                                             \
        const short8 Bf00 = *reinterpret_cast<const short8*>(&Pl[ 0 + cc][      g * 8]); \
        const short8 Bf10 = *reinterpret_cast<const short8*>(&Pl[ 0 + cc][32 + g * 8]); \
        const short8 Bf01 = *reinterpret_cast<const short8*>(&Pl[16 + cc][      g * 8]); \
        const short8 Bf11 = *reinterpret_cast<const short8*>(&Pl[16 + cc][32 + g * 8]); \
        const short8 Bf02 = *reinterpret_cast<const short8*>(&Pl[32 + cc][      g * 8]); \
        const short8 Bf12 = *reinterpret_cast<const short8*>(&Pl[32 + cc][32 + g * 8]); \
        const float ef0 = __expf(E0) * pscale;                               \
        const float ef1 = __expf(E1) * pscale;                               \
        const float ef2 = __expf(E2) * pscale;                               \
        const short8 A00 = MKA(0, 0, ef0), A01 = MKA(0, 1, ef0);             \
        const short8 A10 = MKA(1, 0, ef1), A11 = MKA(1, 1, ef1);             \
        const short8 A20 = MKA(2, 0, ef2), A21 = MKA(2, 1, ef2);             \
        f32x4 z;                                                             \
        DOFRAG(z, A00, A01, 0, 0);                                           \
        { const unsigned pb_ = (unsigned)__builtin_amdgcn_readfirstlane(     \
              (int)__float_as_uint(z[0]));                                   \
          const int ee_ = (int)((pb_ >> 23) & 255u);                         \
          const int kk_ = ee_ - 127;                                         \
          K += kk_; pend = kk_;                                              \
          pscale = __uint_as_float((unsigned)(254 - ee_) << 23); }           \
        WRFRAG(z, 0, 0);                                                     \
        DOFRAG(z, A00, A01, 1, 0); WRFRAG(z, 1, 0);                          \
        DOFRAG(z, A00, A01, 2, 0); WRFRAG(z, 2, 0);                          \
        DOFRAG(z, A10, A11, 0, 1); WRFRAG(z, 0, 1);                          \
        DOFRAG(z, A10, A11, 1, 1); WRFRAG(z, 1, 1);                          \
        DOFRAG(z, A10, A11, 2, 1); WRFRAG(z, 2, 1);                          \
        DOFRAG(z, A20, A21, 0, 2); WRFRAG(z, 0, 2);                          \
        DOFRAG(z, A20, A21, 1, 2); WRFRAG(z, 1, 2);                          \
        DOFRAG(z, A20, A21, 2, 2); WRFRAG(z, 2, 2);                          \
    }                                                                        \
} while (0)

    float sA0, sA1, sA2, sB0, sB1, sB2, sC0, sC1, sC2, sD0, sD1, sD2;
    EMLOAD(0, sA0, sA1, sA2);
    EMLOAD(1, sB0, sB1, sB2);
    EMLOAD(2, sC0, sC1, sC2);
    EMLOAD(3, sD0, sD1, sD2);

#pragma unroll
    for (int q = 0; q < NQ; ++q) {
        const unsigned long long bq = ball[q];
        for (int tt = 0; tt < 64; tt += 4) {
            const int t = q * 64 + tt;
            STEP_BODY((c0 && q == 0 && tt == 0), tt + 0, sA0, sA1, sA2);
            EMLOAD(t + 4, sA0, sA1, sA2);
            STEP_BODY(false, tt + 1, sB0, sB1, sB2);
            EMLOAD(t + 5, sB0, sB1, sB2);
            STEP_BODY(false, tt + 2, sC0, sC1, sC2);
            EMLOAD(t + 6, sC0, sC1, sC2);
            STEP_BODY(false, tt + 3, sD0, sD1, sD2);
            EMLOAD(t + 7, sD0, sD1, sD2);
        }
    }

    // write out the chunk matrix: row j holds Pl[0..47][j] bf16-packed
    if (tid < T_TAGS) {
        const unsigned base = (unsigned)bid * MAT_U32 + tid * 24;
#pragma unroll
        for (int q = 0; q < 6; ++q) {
            uint4 W;
            W.x = (unsigned)Pl[8 * q + 0][tid] | ((unsigned)Pl[8 * q + 1][tid] << 16);
            W.y = (unsigned)Pl[8 * q + 2][tid] | ((unsigned)Pl[8 * q + 3][tid] << 16);
            W.z = (unsigned)Pl[8 * q + 4][tid] | ((unsigned)Pl[8 * q + 5][tid] << 16);
            W.w = (unsigned)Pl[8 * q + 6][tid] | ((unsigned)Pl[8 * q + 7][tid] << 16);
            *reinterpret_cast<uint4*>(&wsP[base + 4 * q]) = W;
        }
    }
    if (tid == 0) wsK[bid] = K - pend;

#undef EMLOAD
#undef MKA
#undef DOFRAG
#undef WRFRAG
#undef STEP_BODY
}

// ---------------------------------------------------------------------------
// Phase 2: per-sequence combine over CCH chunk matrices + endT + log.
// Also adds the numerator's end-transition term (uses wsCnt from phase 1).
// ---------------------------------------------------------------------------
template<int CCH>
__global__ __launch_bounds__(64, 1) void crf_combine_kernel(
    const float* __restrict__ em, const float* __restrict__ startT,
    const float* __restrict__ endT, const unsigned* __restrict__ wsP,
    const int* __restrict__ wsK, const int* __restrict__ wsCnt,
    const int* __restrict__ tags, float* __restrict__ out)
{
    const int b = blockIdx.x, tid = threadIdx.x;
    const int j = (tid < T_TAGS) ? tid : 0;
    float v = (tid < T_TAGS) ? __expf(startT[j] + em[(size_t)b * T_TAGS + j]) : 0.f;
    int K2 = 0;
    for (int c = 0; c < CCH; ++c) {
        const unsigned base = (unsigned)(b * CCH + c) * MAT_U32 + j * 24;
        uint4 W[6];
#pragma unroll
        for (int q = 0; q < 6; ++q)
            W[q] = *reinterpret_cast<const uint4*>(&wsP[base + 4 * q]);
        float a0 = 0.f, a1 = 0.f;
#pragma unroll
        for (int q = 0; q < 6; ++q) {
            const unsigned wv[4] = {W[q].x, W[q].y, W[q].z, W[q].w};
#pragma unroll
            for (int r = 0; r < 4; ++r) {
                const int i = q * 8 + r * 2;
                const float p0 = __uint_as_float(wv[r] << 16);
                const float p1 = __uint_as_float(wv[r] & 0xFFFF0000u);
                a0 = fmaf(__uint_as_float(__builtin_amdgcn_readlane(__float_as_uint(v), i)), p0, a0);
                a1 = fmaf(__uint_as_float(__builtin_amdgcn_readlane(__float_as_uint(v), i + 1)), p1, a1);
            }
        }
        const float vn = a0 + a1;
        const unsigned pb = (unsigned)__builtin_amdgcn_readfirstlane((int)__float_as_uint(vn));
        const int ee = (int)((pb >> 23) & 255u);
        const float sc = __uint_as_float((unsigned)(254 - ee) << 23);
        v = vn * sc;
        K2 += (ee - 127) + wsK[b * CCH + c];
    }
    float contrib = (tid < T_TAGS) ? v * __expf(endT[j]) : 0.f;
#pragma unroll
    for (int off = 32; off > 0; off >>= 1) contrib += __shfl_down(contrib, off);
    if (tid == 0) {
        const int cnt  = wsCnt[b];
        const int last = tags[(size_t)(cnt - 1) * B_SZ + b];
        const double den = (double)K2 * 0.6931471805599453 + (double)__logf(contrib);
        atomicAdd(out, endT[last] + (float)(-den));
    }
}

// ---------------------------------------------------------------------------
// Numerator: emission scores of chosen tags + transition scores + start terms
// ---------------------------------------------------------------------------
__global__ void crf_num_kernel(
    const float* __restrict__ em, const int* __restrict__ tags,
    const int* __restrict__ mask, const float* __restrict__ startT,
    const float* __restrict__ trans, float* __restrict__ out)
{
    const int N = S_LEN * B_SZ;
    float acc = 0.f;
    for (int idx = blockIdx.x * blockDim.x + threadIdx.x; idx < N;
         idx += gridDim.x * blockDim.x) {
        const int t = tags[idx];
        const float e = em[(size_t)idx * T_TAGS + t];
        if (idx < B_SZ) {                         // s == 0
            acc += e + startT[t];
        } else if (mask[idx] != 0) {
            acc += e + trans[tags[idx - B_SZ] * T_TAGS + t];
        }
    }
#pragma unroll
    for (int off = 32; off > 0; off >>= 1)
        acc += __shfl_down(acc, off);
    if ((threadIdx.x & 63) == 0) atomicAdd(out, acc);
}

extern "C" void kernel_launch(void* const* d_in, const int* in_sizes, int n_in,
                              void* d_out, int out_size, void* d_ws, size_t ws_size,
                              hipStream_t stream)
{
    const float* em     = (const float*)d_in[0];
    const int*   tags   = (const int*)  d_in[1];
    const int*   mask   = (const int*)  d_in[2];
    const float* startT = (const float*)d_in[3];
    const float* endT   = (const float*)d_in[4];
    const float* trans  = (const float*)d_in[5];
    float* out = (float*)d_out;

    int*      wsCnt = (int*)((char*)d_ws + WS_CNT_OFF);
    int*      wsK   = (int*)((char*)d_ws + WS_K_OFF);
    unsigned* wsP   = (unsigned*)((char*)d_ws + WS_P_OFF);

    hipMemsetAsync(out, 0, sizeof(float), stream);
    hipMemsetAsync(wsCnt, 0, B_SZ * sizeof(int), stream);

    const size_t need16 = (size_t)WS_P_OFF + (size_t)(B_SZ * 16) * (MAT_U32 * 4);
    if (ws_size >= need16) {
        crf_chunk_kernel<16><<<B_SZ * 16, 64, 0, stream>>>(em, mask, trans, wsP, wsK, wsCnt);
        crf_num_kernel<<<512, 256, 0, stream>>>(em, tags, mask, startT, trans, out);
        crf_combine_kernel<16><<<B_SZ, 64, 0, stream>>>(em, startT, endT, wsP, wsK, wsCnt, tags, out);
    } else {
        crf_chunk_kernel<8><<<B_SZ * 8, 64, 0, stream>>>(em, mask, trans, wsP, wsK, wsCnt);
        crf_num_kernel<<<512, 256, 0, stream>>>(em, tags, mask, startT, trans, out);
        crf_combine_kernel<8><<<B_SZ, 64, 0, stream>>>(em, startT, endT, wsP, wsK, wsCnt, tags, out);
    }
}

// Round 7
// 226.826 us; speedup vs baseline: 6.1460x; 1.2366x over previous
//
#include <hip/hip_runtime.h>
#include <hip/hip_bf16.h>
#include <math.h>

#define S_LEN  2048
#define B_SZ   256
#define T_TAGS 48
#define MAT_U32 1152          // 48 rows * 24 u32 (bf16-packed 48x48)

#define WS_CNT_OFF 0          // 256 ints
#define WS_K_OFF   1024       // up to 8192 ints (ends < 64KB)
#define WS_P_OFF   65536      // chunk matrices

using short8 = __attribute__((ext_vector_type(8))) short;
using f32x4  = __attribute__((ext_vector_type(4))) float;

// single-instruction bf16 pack (gfx950 V_CVT_PK_BF16_F32)
__device__ __forceinline__ unsigned cvtpk(float lo, float hi) {
    unsigned r;
    asm("v_cvt_pk_bf16_f32 %0, %1, %2" : "=v"(r) : "v"(lo), "v"(hi));
    return r;
}

// ---------------------------------------------------------------------------
// Phase 1: per-chunk transfer matrix P_c (one wave per chunk).
// State Q[n][k] (48x48 bf16, k padded to 64) lives in LDS, subtiled so that
//   read  frag(nt,kt): ds_read_b128 at  nt*2048 + kt*1024 + tid*16   (contig)
//   write frag(jt,nt): ds_write_b64 at  nt*2048 + ((2jt+(g>>1))*16+cc)*16+(g&1)*8
// => zero bank conflicts. Per step: 6 ds_read_b128, 18 MFMA 16x16x32 bf16,
// 12 exp, ~48 mul, 18 v_cvt_pk_bf16_f32, 9 ds_write_b64. Same-wave DS
// ordering => no barriers. Power-of-2 renorm folded forward (pscale, int K).
// ---------------------------------------------------------------------------
template<int CCH>
__global__ __launch_bounds__(64, 4) void crf_chunk_kernel(
    const float* __restrict__ em, const int* __restrict__ mask,
    const float* __restrict__ trans, unsigned* __restrict__ wsP,
    int* __restrict__ wsK, int* __restrict__ wsCnt)
{
    constexpr int LCH = S_LEN / CCH;
    constexpr int NQ  = LCH / 64;
    const int bid = blockIdx.x;
    const int b = bid / CCH, c = bid % CCH;
    const int tid = threadIdx.x;
    const int cc = tid & 15, g = tid >> 4;
    const int start = c * LCH;

    __shared__ __align__(16) uint4 lds4[384];   // 6144 B
    char* Lc = (char*)lds4;

    // zero everything (incl. k in [48,64) pad, never written again)
#pragma unroll
    for (int i = 0; i < 6; ++i) lds4[tid + 64 * i] = make_uint4(0u, 0u, 0u, 0u);
    __builtin_amdgcn_wave_barrier();
    // identity Q[n][n] = 1.0bf16
    if (tid < T_TAGS)
        *(unsigned short*)(Lc + (tid >> 4) * 2048 +
                           ((tid >> 3) * 16 + (tid & 15)) * 16 + (tid & 7) * 2) = 0x3F80;
    __builtin_amdgcn_wave_barrier();

    // constant A fragments: A[j][k] = expT[k][j], j = jt*16+cc, k = kt*32+g*8+e
    short8 Afr[3][2];
#pragma unroll
    for (int jt = 0; jt < 3; ++jt) {
        const int j = jt * 16 + cc;
#pragma unroll
        for (int kt = 0; kt < 2; ++kt) {
            unsigned u[4];
#pragma unroll
            for (int h = 0; h < 4; ++h) {
                const int k0 = kt * 32 + g * 8 + 2 * h;
                const float lo = (k0     < T_TAGS) ? __expf(trans[k0 * T_TAGS + j]) : 0.f;
                const float hi = (k0 + 1 < T_TAGS) ? __expf(trans[(k0 + 1) * T_TAGS + j]) : 0.f;
                u[h] = cvtpk(lo, hi);
            }
            uint4 uu = make_uint4(u[0], u[1], u[2], u[3]);
            Afr[jt][kt] = *reinterpret_cast<short8*>(&uu);
        }
    }

    // mask ballots
    unsigned long long ball[NQ];
    int cnt = 0;
#pragma unroll
    for (int q = 0; q < NQ; ++q) {
        const int s = start + q * 64 + tid;
        ball[q] = __ballot(mask[s * B_SZ + b] != 0);
        cnt += (int)__popcll(ball[q]);
    }
    if (tid == 0) atomicAdd(&wsCnt[b], cnt);
    if (c == 0) ball[0] &= ~1ull;      // global s=0 is the init, not a transition

    int K = 0, pend = 0;
    float pscale = 1.0f;
    const f32x4 fz = {0.f, 0.f, 0.f, 0.f};
    const size_t embase = (size_t)b * T_TAGS + 4 * g;

    auto emload = [&](int t, f32x4& d0, f32x4& d1, f32x4& d2) {
        int ss = start + t; if (ss > S_LEN - 1) ss = S_LEN - 1;
        const float* p = em + (size_t)ss * (B_SZ * T_TAGS) + embase;
        d0 = *(const f32x4*)(p);
        d1 = *(const f32x4*)(p + 16);
        d2 = *(const f32x4*)(p + 32);
    };

    auto step = [&](bool on, const f32x4& e0, const f32x4& e1, const f32x4& e2) {
        if (!on) return;
        // B fragments: wave-contiguous 1KB reads, conflict-free
        const short8 B00 = *(const short8*)(Lc +        tid * 16);
        const short8 B01 = *(const short8*)(Lc + 1024 + tid * 16);
        const short8 B10 = *(const short8*)(Lc + 2048 + tid * 16);
        const short8 B11 = *(const short8*)(Lc + 3072 + tid * 16);
        const short8 B20 = *(const short8*)(Lc + 4096 + tid * 16);
        const short8 B21 = *(const short8*)(Lc + 5120 + tid * 16);
        const float ps = pscale;
        float ef0[4], ef1[4], ef2[4];
#pragma unroll
        for (int r = 0; r < 4; ++r) {
            ef0[r] = __expf(e0[r]) * ps;
            ef1[r] = __expf(e1[r]) * ps;
            ef2[r] = __expf(e2[r]) * ps;
        }
        f32x4 z;
#define DOFRAG(JT, NT, BN0, BN1, EF, PROBE_)                                   \
        z = __builtin_amdgcn_mfma_f32_16x16x32_bf16(Afr[JT][0], BN0, fz, 0, 0, 0); \
        z = __builtin_amdgcn_mfma_f32_16x16x32_bf16(Afr[JT][1], BN1, z,  0, 0, 0); \
        if (PROBE_) {                                                          \
            const unsigned pb_ = (unsigned)__builtin_amdgcn_readfirstlane(     \
                (int)__float_as_uint(z[0]));                                   \
            const int ee_ = (int)((pb_ >> 23) & 255u);                         \
            const int kk_ = ee_ - 127;                                         \
            K += kk_; pend = kk_;                                              \
            pscale = __uint_as_float((unsigned)(254 - ee_) << 23);             \
        }                                                                      \
        *(uint2*)(Lc + (NT) * 2048 + ((2 * (JT) + (g >> 1)) * 16 + cc) * 16 +  \
                  (g & 1) * 8) =                                               \
            make_uint2(cvtpk(z[0] * EF[0], z[1] * EF[1]),                      \
                       cvtpk(z[2] * EF[2], z[3] * EF[3]))

        DOFRAG(0, 0, B00, B01, ef0, true);
        DOFRAG(0, 1, B10, B11, ef0, false);
        DOFRAG(0, 2, B20, B21, ef0, false);
        DOFRAG(1, 0, B00, B01, ef1, false);
        DOFRAG(1, 1, B10, B11, ef1, false);
        DOFRAG(1, 2, B20, B21, ef1, false);
        DOFRAG(2, 0, B00, B01, ef2, false);
        DOFRAG(2, 1, B10, B11, ef2, false);
        DOFRAG(2, 2, B20, B21, ef2, false);
#undef DOFRAG
    };

    // 2-deep em software pipeline
    f32x4 a0, a1, a2, b0, b1, b2;
    emload(0, a0, a1, a2);
    emload(1, b0, b1, b2);

#pragma unroll
    for (int q = 0; q < NQ; ++q) {
        const unsigned long long bq = ball[q];
        for (int tt = 0; tt < 64; tt += 2) {
            const int t = q * 64 + tt;
            step(((bq >> tt) & 1ull) != 0, a0, a1, a2);
            emload(t + 2, a0, a1, a2);
            step(((bq >> (tt + 1)) & 1ull) != 0, b0, b1, b2);
            emload(t + 3, b0, b1, b2);
        }
    }

    // readout: ws row j(=tid) = Q[:, j], i-pairs packed bf16x2
    if (tid < T_TAGS) {
        unsigned w[24];
#pragma unroll
        for (int p = 0; p < 24; ++p) {
            const int i0 = 2 * p, i1 = i0 + 1;
            const unsigned lo = *(const unsigned short*)(Lc + (i0 >> 4) * 2048 +
                ((tid >> 3) * 16 + (i0 & 15)) * 16 + (tid & 7) * 2);
            const unsigned hi = *(const unsigned short*)(Lc + (i1 >> 4) * 2048 +
                ((tid >> 3) * 16 + (i1 & 15)) * 16 + (tid & 7) * 2);
            w[p] = lo | (hi << 16);
        }
        const unsigned base = (unsigned)bid * MAT_U32 + (unsigned)tid * 24;
#pragma unroll
        for (int qq = 0; qq < 6; ++qq)
            *reinterpret_cast<uint4*>(&wsP[base + 4 * qq]) =
                make_uint4(w[4 * qq], w[4 * qq + 1], w[4 * qq + 2], w[4 * qq + 3]);
    }
    if (tid == 0) wsK[bid] = K - pend;
}

// ---------------------------------------------------------------------------
// Phase 2: per-sequence combine over CCH chunk matrices + endT + log.
// Also adds the numerator's end-transition term (uses wsCnt from phase 1).
// ---------------------------------------------------------------------------
template<int CCH>
__global__ __launch_bounds__(64, 1) void crf_combine_kernel(
    const float* __restrict__ em, const float* __restrict__ startT,
    const float* __restrict__ endT, const unsigned* __restrict__ wsP,
    const int* __restrict__ wsK, const int* __restrict__ wsCnt,
    const int* __restrict__ tags, float* __restrict__ out)
{
    const int b = blockIdx.x, tid = threadIdx.x;
    const int j = (tid < T_TAGS) ? tid : 0;
    float v = (tid < T_TAGS) ? __expf(startT[j] + em[(size_t)b * T_TAGS + j]) : 0.f;
    int K2 = 0;
    for (int c = 0; c < CCH; ++c) {
        const unsigned base = (unsigned)(b * CCH + c) * MAT_U32 + j * 24;
        uint4 W[6];
#pragma unroll
        for (int q = 0; q < 6; ++q)
            W[q] = *reinterpret_cast<const uint4*>(&wsP[base + 4 * q]);
        float a0 = 0.f, a1 = 0.f;
#pragma unroll
        for (int q = 0; q < 6; ++q) {
            const unsigned wv[4] = {W[q].x, W[q].y, W[q].z, W[q].w};
#pragma unroll
            for (int r = 0; r < 4; ++r) {
                const int i = q * 8 + r * 2;
                const float p0 = __uint_as_float(wv[r] << 16);
                const float p1 = __uint_as_float(wv[r] & 0xFFFF0000u);
                a0 = fmaf(__uint_as_float(__builtin_amdgcn_readlane(__float_as_uint(v), i)), p0, a0);
                a1 = fmaf(__uint_as_float(__builtin_amdgcn_readlane(__float_as_uint(v), i + 1)), p1, a1);
            }
        }
        const float vn = a0 + a1;
        const unsigned pb = (unsigned)__builtin_amdgcn_readfirstlane((int)__float_as_uint(vn));
        const int ee = (int)((pb >> 23) & 255u);
        const float sc = __uint_as_float((unsigned)(254 - ee) << 23);
        v = vn * sc;
        K2 += (ee - 127) + wsK[b * CCH + c];
    }
    float contrib = (tid < T_TAGS) ? v * __expf(endT[j]) : 0.f;
#pragma unroll
    for (int off = 32; off > 0; off >>= 1) contrib += __shfl_down(contrib, off);
    if (tid == 0) {
        const int cnt  = wsCnt[b];
        const int last = tags[(size_t)(cnt - 1) * B_SZ + b];
        const double den = (double)K2 * 0.6931471805599453 + (double)__logf(contrib);
        atomicAdd(out, endT[last] + (float)(-den));
    }
}

// ---------------------------------------------------------------------------
// Numerator: emission scores of chosen tags + transition scores + start terms
// ---------------------------------------------------------------------------
__global__ void crf_num_kernel(
    const float* __restrict__ em, const int* __restrict__ tags,
    const int* __restrict__ mask, const float* __restrict__ startT,
    const float* __restrict__ trans, float* __restrict__ out)
{
    const int N = S_LEN * B_SZ;
    float acc = 0.f;
    for (int idx = blockIdx.x * blockDim.x + threadIdx.x; idx < N;
         idx += gridDim.x * blockDim.x) {
        const int t = tags[idx];
        const float e = em[(size_t)idx * T_TAGS + t];
        if (idx < B_SZ) {                         // s == 0
            acc += e + startT[t];
        } else if (mask[idx] != 0) {
            acc += e + trans[tags[idx - B_SZ] * T_TAGS + t];
        }
    }
#pragma unroll
    for (int off = 32; off > 0; off >>= 1)
        acc += __shfl_down(acc, off);
    if ((threadIdx.x & 63) == 0) atomicAdd(out, acc);
}

extern "C" void kernel_launch(void* const* d_in, const int* in_sizes, int n_in,
                              void* d_out, int out_size, void* d_ws, size_t ws_size,
                              hipStream_t stream)
{
    const float* em     = (const float*)d_in[0];
    const int*   tags   = (const int*)  d_in[1];
    const int*   mask   = (const int*)  d_in[2];
    const float* startT = (const float*)d_in[3];
    const float* endT   = (const float*)d_in[4];
    const float* trans  = (const float*)d_in[5];
    float* out = (float*)d_out;

    int*      wsCnt = (int*)((char*)d_ws + WS_CNT_OFF);
    int*      wsK   = (int*)((char*)d_ws + WS_K_OFF);
    unsigned* wsP   = (unsigned*)((char*)d_ws + WS_P_OFF);

    hipMemsetAsync(out, 0, sizeof(float), stream);
    hipMemsetAsync(wsCnt, 0, B_SZ * sizeof(int), stream);

    const size_t need16 = (size_t)WS_P_OFF + (size_t)(B_SZ * 16) * (MAT_U32 * 4);
    if (ws_size >= need16) {
        crf_chunk_kernel<16><<<B_SZ * 16, 64, 0, stream>>>(em, mask, trans, wsP, wsK, wsCnt);
        crf_num_kernel<<<512, 256, 0, stream>>>(em, tags, mask, startT, trans, out);
        crf_combine_kernel<16><<<B_SZ, 64, 0, stream>>>(em, startT, endT, wsP, wsK, wsCnt, tags, out);
    } else {
        crf_chunk_kernel<8><<<B_SZ * 8, 64, 0, stream>>>(em, mask, trans, wsP, wsK, wsCnt);
        crf_num_kernel<<<512, 256, 0, stream>>>(em, tags, mask, startT, trans, out);
        crf_combine_kernel<8><<<B_SZ, 64, 0, stream>>>(em, startT, endT, wsP, wsK, wsCnt, tags, out);
    }
}